// Round 3
// baseline (122.016 us; speedup 1.0000x reference)
//
#include <hip/hip_runtime.h>
#include <stdint.h>

#define D 128
#define TM 64
#define GRID 768        // 3 blocks/CU * 256 CU
#define NTHREADS 256
#define PPS 17          // pp row stride (pad to kill bank conflicts)

typedef float f32x4 __attribute__((ext_vector_type(4)));
typedef short s16x8 __attribute__((ext_vector_type(8)));
typedef uint32_t u32x2 __attribute__((ext_vector_type(2)));

__device__ __forceinline__ uint32_t f2bf_u(float f) {
    union { float f; uint32_t u; } v; v.f = f;
    return (v.u + 0x7fffu + ((v.u >> 16) & 1u)) >> 16;   // RNE
}
__device__ __forceinline__ short f2bf(float f) { return (short)f2bf_u(f); }
__device__ __forceinline__ uint32_t cvt_pk_bf16(float lo, float hi) {
    uint32_t r;
    asm("v_cvt_pk_bf16_f32 %0, %1, %2" : "=v"(r) : "v"(lo), "v"(hi));
    return r;
}

__global__ __launch_bounds__(NTHREADS, 3)
void gate_agg_kernel(const float* __restrict__ X,
                     const int* __restrict__ bidx,
                     const float* __restrict__ W1,
                     const float* __restrict__ b1,
                     const float* __restrict__ W2,
                     const float* __restrict__ b2,
                     float* __restrict__ out,
                     int NT)
{
    __shared__ short xtile[TM * D];        // bf16, 16B-chunk XOR-swizzled, 16 KB
    __shared__ float pp[64 * PPS];         // phase-2 partials [row][16], padded
    __shared__ u32x2 gidL[TM];             // {gate bits, seg}
    __shared__ int   idxL[TM];

    const int tid = threadIdx.x;
    const int l = tid & 63;
    const int w = tid >> 6;
    const int l15 = l & 15;
    const int lk = l >> 4;                 // k-chunk id within MFMA frags

    // ---- one-time: W1 B-fragments for this wave's 2 col-tiles -> registers
    // frag (j,kt): lane l holds W1[kt*32 + lk*8 + e][(2w+j)*16 + l15], e=0..7
    s16x8 bfr[2][4];
    #pragma unroll
    for (int j = 0; j < 2; ++j) {
        const int n = (2 * w + j) * 16 + l15;
        #pragma unroll
        for (int kt = 0; kt < 4; ++kt) {
            #pragma unroll
            for (int e = 0; e < 8; ++e)
                bfr[j][kt][e] = f2bf(W1[(kt * 32 + lk * 8 + e) * D + n]);
        }
    }
    float b1v[2], w2v[2];
    #pragma unroll
    for (int j = 0; j < 2; ++j) {
        b1v[j] = b1[(2 * w + j) * 16 + l15];
        w2v[j] = W2[(2 * w + j) * 16 + l15];
    }
    const float b2s = b2[0];

    // balanced contiguous tile range
    const int q = NT / GRID, rem = NT % GRID;
    int t0, t1;
    if ((int)blockIdx.x < rem) { t0 = blockIdx.x * (q + 1); t1 = t0 + q + 1; }
    else { t0 = rem * (q + 1) + ((int)blockIdx.x - rem) * q; t1 = t0 + q; }

    // phase-3 ownership: 4 cols x 8 rows per thread
    const int cc = tid & 31;               // col group: cols 4cc..4cc+3
    const int rg = tid >> 5;               // rows rg*8..rg*8+7
    float acc3[4] = {0.f, 0.f, 0.f, 0.f};
    int cur = -1;

    // ---- prologue: prefetch tile t0
    f32x4 v[8];
    int ridx = 0;
    if (t0 < t1) {
        const float* xg = X + (size_t)t0 * TM * D;
        #pragma unroll
        for (int j = 0; j < 8; ++j)
            v[j] = *(const f32x4*)(xg + (size_t)(j * 256 + tid) * 4);
        if (tid < TM) ridx = bidx[(size_t)t0 * TM + tid];
    }

    for (int t = t0; t < t1; ++t) {
        // ---- stage: regs -> bf16 swizzled LDS ----
        #pragma unroll
        for (int j = 0; j < 8; ++j) {
            int qc = j * 256 + tid;
            int row = qc >> 5, cq = qc & 31;
            int c2 = cq >> 1, h = cq & 1;
            u32x2 wv;
            wv[0] = cvt_pk_bf16(v[j][0], v[j][1]);
            wv[1] = cvt_pk_bf16(v[j][2], v[j][3]);
            *(u32x2*)((char*)xtile + row * 256 + ((c2 ^ (row & 15)) << 4) + h * 8) = wv;
        }
        if (tid < TM) idxL[tid] = ridx;
        __syncthreads();                                   // B1: tile staged

        // ---- T14: issue next tile's loads (overlap phases 1-3)
        if (t + 1 < t1) {
            const float* xg = X + (size_t)(t + 1) * TM * D;
            #pragma unroll
            for (int j = 0; j < 8; ++j)
                v[j] = *(const f32x4*)(xg + (size_t)(j * 256 + tid) * 4);
            if (tid < TM) ridx = bidx[(size_t)(t + 1) * TM + tid];
        }

        // ---- phase 1: wave computes all 64 rows x its 32 cols ----
        f32x4 acc[4][2];
        #pragma unroll
        for (int rf = 0; rf < 4; ++rf) { acc[rf][0] = (f32x4)0.f; acc[rf][1] = (f32x4)0.f; }

        #pragma unroll
        for (int kt = 0; kt < 4; ++kt) {
            const int kc = kt * 4 + lk;
            #pragma unroll
            for (int rf = 0; rf < 4; ++rf) {
                const int R = rf * 16 + l15;
                s16x8 a = *(const s16x8*)((const char*)xtile + R * 256 + ((kc ^ l15) << 4));
                acc[rf][0] = __builtin_amdgcn_mfma_f32_16x16x32_bf16(a, bfr[0][kt], acc[rf][0], 0, 0, 0);
                acc[rf][1] = __builtin_amdgcn_mfma_f32_16x16x32_bf16(a, bfr[1][kt], acc[rf][1], 0, 0, 0);
            }
        }

        // ---- phase 2a: partial dot with W2, quad-reduce, write pp ----
        #pragma unroll
        for (int rf = 0; rf < 4; ++rf) {
            float pr[4];
            #pragma unroll
            for (int r = 0; r < 4; ++r) {
                float s = 0.f;
                #pragma unroll
                for (int j = 0; j < 2; ++j) {
                    float h = acc[rf][j][r] + b1v[j];
                    h = fmaxf(h, 0.f);
                    s = fmaf(h, w2v[j], s);
                }
                s += __shfl_xor(s, 1, 64);                 // DPP quad perm
                s += __shfl_xor(s, 2, 64);
                pr[r] = s;                                 // quad-sum
            }
            // lane l writes pr[l&3] for row rf*16 + lk*4 + (l&3), col w*4 + ((l>>2)&3)
            float val = pr[0];
            val = ((l & 3) == 1) ? pr[1] : val;
            val = ((l & 3) == 2) ? pr[2] : val;
            val = ((l & 3) == 3) ? pr[3] : val;
            pp[(rf * 16 + lk * 4 + (l & 3)) * PPS + w * 4 + ((l >> 2) & 3)] = val;
        }
        __syncthreads();                                   // B2: pp complete

        // ---- phase 2b: wave 0 finishes gate ----
        if (tid < TM) {
            float s = 0.f;
            #pragma unroll
            for (int c = 0; c < 16; ++c) s += pp[tid * PPS + c];
            float g = 1.f / (1.f + __expf(-(s + b2s)));
            u32x2 gi; gi[0] = __float_as_uint(g); gi[1] = (uint32_t)idxL[tid];
            gidL[tid] = gi;
        }
        __syncthreads();                                   // B3: gates ready

        // ---- phase 3: segmented accumulate, 4 cols x 8 rows, b64 reads ----
        #pragma unroll
        for (int rr = 0; rr < 8; ++rr) {
            int r = rg * 8 + rr;
            u32x2 gi = gidL[r];
            int seg = (int)gi[1];
            float g = __uint_as_float(gi[0]);
            if (seg != cur) {
                if (cur >= 0) {
                    #pragma unroll
                    for (int i = 0; i < 4; ++i)
                        atomicAdd(out + (size_t)cur * D + 4 * cc + i, acc3[i]);
                }
                acc3[0] = acc3[1] = acc3[2] = acc3[3] = 0.f;
                cur = seg;
            }
            u32x2 xw = *(const u32x2*)((const char*)xtile + r * 256 +
                        (((cc >> 1) ^ (r & 15)) << 4) + (cc & 1) * 8);
            float f0 = __uint_as_float(xw[0] << 16);
            float f1 = __uint_as_float(xw[0] & 0xffff0000u);
            float f2 = __uint_as_float(xw[1] << 16);
            float f3 = __uint_as_float(xw[1] & 0xffff0000u);
            acc3[0] = fmaf(g, f0, acc3[0]);
            acc3[1] = fmaf(g, f1, acc3[1]);
            acc3[2] = fmaf(g, f2, acc3[2]);
            acc3[3] = fmaf(g, f3, acc3[3]);
        }
        __syncthreads();                                   // B4: xtile/idxL reusable
    }
    if (cur >= 0) {
        #pragma unroll
        for (int i = 0; i < 4; ++i)
            atomicAdd(out + (size_t)cur * D + 4 * cc + i, acc3[i]);
    }
}

extern "C" void kernel_launch(void* const* d_in, const int* in_sizes, int n_in,
                              void* d_out, int out_size, void* d_ws, size_t ws_size,
                              hipStream_t stream) {
    const float* X    = (const float*)d_in[0];
    const int*   bidx = (const int*)d_in[1];
    const float* W1   = (const float*)d_in[2];
    const float* b1   = (const float*)d_in[3];
    const float* W2   = (const float*)d_in[4];
    const float* b2   = (const float*)d_in[5];
    float* out = (float*)d_out;

    const int N  = in_sizes[0] / D;      // 1,000,000
    const int NT = N / TM;               // 15,625 tiles

    hipMemsetAsync(d_out, 0, (size_t)out_size * sizeof(float), stream);
    gate_agg_kernel<<<GRID, NTHREADS, 0, stream>>>(X, bidx, W1, b1, W2, b2, out, NT);
}